// Round 4
// baseline (126.201 us; speedup 1.0000x reference)
//
#include <hip/hip_runtime.h>
#include <hip/hip_bf16.h>

// out[i] = x_i @ Q @ x_i, x [1024,2048] fp32 binary, Q [2048,2048] fp32.
// Identity: x^T Q x == x^T Q^T x -> MFMA B-operand (N x K) = row-major Q.
// Round 4: 32x32x16 MFMA (2x FLOP per LDS byte), 64x128 wave tile (acc 128
// VGPR), 128x256 block tile, bf16 prep kernel + global_load_lds staging
// (zero staging VGPRs / zero cvt in hot loop), XOR bank swizzle.

#define B_ROWS 1024
#define N_BITS 2048

#define BM 128
#define BN 256
#define BK 64
#define KSPLIT 8
#define KPER (N_BITS / KSPLIT)   // 256
#define KITERS (KPER / BK)       // 4

typedef __bf16 bf16_t;
typedef __bf16 bf16x8 __attribute__((ext_vector_type(8)));
typedef float f32x16 __attribute__((ext_vector_type(16)));

__device__ __forceinline__ void load16_to_lds(const void* g, void* l) {
  __builtin_amdgcn_global_load_lds(
      (__attribute__((address_space(1))) void*)(g),
      (__attribute__((address_space(3))) void*)(l),
      16, 0, 0);
}

// prep: fp32 -> bf16 for x (2M) and Q (4M) into ws; zero out[1024].
__global__ __launch_bounds__(256) void prep_kernel(
    const float* __restrict__ x, const float* __restrict__ Q,
    bf16_t* __restrict__ xb, bf16_t* __restrict__ qb, float* __restrict__ out) {
  const int tid = blockIdx.x * 256 + threadIdx.x;
  if (tid < B_ROWS) out[tid] = 0.0f;
  const int XTH = (B_ROWS * N_BITS) / 8;
  const float* src;
  bf16_t* dst;
  if (tid < XTH) {
    size_t o = (size_t)tid * 8;
    src = x + o;
    dst = xb + o;
  } else {
    size_t o = (size_t)(tid - XTH) * 8;
    src = Q + o;
    dst = qb + o;
  }
  float4 v0 = ((const float4*)src)[0];
  float4 v1 = ((const float4*)src)[1];
  union { int4 i4; __hip_bfloat16 h[8]; } u;
  u.h[0] = __float2bfloat16(v0.x);
  u.h[1] = __float2bfloat16(v0.y);
  u.h[2] = __float2bfloat16(v0.z);
  u.h[3] = __float2bfloat16(v0.w);
  u.h[4] = __float2bfloat16(v1.x);
  u.h[5] = __float2bfloat16(v1.y);
  u.h[6] = __float2bfloat16(v1.z);
  u.h[7] = __float2bfloat16(v1.w);
  ((int4*)dst)[0] = u.i4;
}

// GEMM S = Xb @ Qb^T (32x32x16 frags) + fused row-dot + atomicAdd.
// 4 waves in 2x2; each wave owns a 64x128 tile = 2x4 frags of 32x32.
__global__ __launch_bounds__(256, 2) void qubo_kernel(
    const bf16_t* __restrict__ Xb, const bf16_t* __restrict__ Qb,
    float* __restrict__ out) {
  __shared__ bf16_t ldsA[BM * BK];   // 16 KB
  __shared__ bf16_t ldsB[BN * BK];   // 32 KB

  const int tid  = threadIdx.x;
  const int lane = tid & 63;
  const int wave = tid >> 6;
  const int wr   = wave >> 1;    // m-half (0..1)
  const int wc   = wave & 1;     // n-half (0..1)
  const int ln31 = lane & 31;
  const int l5   = lane >> 5;    // 0..1

  const int m0    = blockIdx.y * BM;
  const int n0    = blockIdx.x * BN;
  const int kbase = blockIdx.z * KPER;

  // Staging: 48 groups of 8 rows x 8 chunks (16B each); 12 wave-instructions
  // per wave per iter. LDS dest is linear (base + lane*16B) as required;
  // the GLOBAL chunk is XOR-swizzled so LDS slot s of row r holds global
  // chunk s ^ (r&7)  -> conflict-free frag ds_read_b128 later.
  const int srow8 = lane >> 3;            // row within 8-row group
  const int gchnk = (lane & 7) ^ srow8;   // swizzled global chunk (rowbase%8==0)

  f32x16 acc[2][4];
#pragma unroll
  for (int i = 0; i < 2; ++i)
#pragma unroll
    for (int j = 0; j < 4; ++j)
#pragma unroll
      for (int r = 0; r < 16; ++r) acc[i][j][r] = 0.f;

  for (int kt = 0; kt < KITERS; ++kt) {
    const int k0 = kbase + kt * BK;
#pragma unroll
    for (int i = 0; i < 12; ++i) {
      const int q = wave * 12 + i;        // 0..47: q<16 -> A rows, else B rows
      if (q < 16) {
        const int r = q * 8 + srow8;      // A tile row 0..127
        load16_to_lds(Xb + (size_t)(m0 + r) * N_BITS + k0 + gchnk * 8,
                      ldsA + q * 512 + lane * 8);
      } else {
        const int r = (q - 16) * 8 + srow8;  // B tile row 0..255
        load16_to_lds(Qb + (size_t)(n0 + r) * N_BITS + k0 + gchnk * 8,
                      ldsB + (q - 16) * 512 + lane * 8);
      }
    }
    __syncthreads();

#pragma unroll
    for (int ks = 0; ks < 4; ++ks) {
      // frag: lane holds [row = ln31][k = l5*8 + j]; chunk = ks*2 + l5,
      // un-swizzle with ^ (row&7) = ^ (lane&7)
      const int ch = ((ks * 2 + l5) ^ (lane & 7)) * 8;
      bf16x8 a[2], b[4];
#pragma unroll
      for (int mi = 0; mi < 2; ++mi)
        a[mi] = *(const bf16x8*)&ldsA[(wr * 64 + mi * 32 + ln31) * BK + ch];
#pragma unroll
      for (int ni = 0; ni < 4; ++ni)
        b[ni] = *(const bf16x8*)&ldsB[(wc * 128 + ni * 32 + ln31) * BK + ch];
#pragma unroll
      for (int mi = 0; mi < 2; ++mi)
#pragma unroll
        for (int ni = 0; ni < 4; ++ni)
          acc[mi][ni] = __builtin_amdgcn_mfma_f32_32x32x16_bf16(
              a[mi], b[ni], acc[mi][ni], 0, 0, 0);
    }
    __syncthreads();
  }

  // Epilogue. 32x32 C/D layout: col = lane&31, row = (r&3) + 8*(r>>2) + 4*(lane>>5).
  // Each (mi, r, half) is a distinct row; reduce over the 32 lanes of the half
  // (xor masks 1..16 keep lane>>5 fixed), 1 atomic per row per block.
#pragma unroll
  for (int mi = 0; mi < 2; ++mi) {
#pragma unroll
    for (int r = 0; r < 16; ++r) {
      const int row = m0 + wr * 64 + mi * 32 + (r & 3) + 8 * (r >> 2) + 4 * l5;
      float s = 0.f;
#pragma unroll
      for (int ni = 0; ni < 4; ++ni) {
        const int col = n0 + wc * 128 + ni * 32 + ln31;
        s += acc[mi][ni][r] * (float)Xb[(size_t)row * N_BITS + col];  // exact: binary
      }
      s += __shfl_xor(s, 1);
      s += __shfl_xor(s, 2);
      s += __shfl_xor(s, 4);
      s += __shfl_xor(s, 8);
      s += __shfl_xor(s, 16);
      if (ln31 == 0) atomicAdd(&out[row], s);
    }
  }
}

extern "C" void kernel_launch(void* const* d_in, const int* in_sizes, int n_in,
                              void* d_out, int out_size, void* d_ws, size_t ws_size,
                              hipStream_t stream) {
  const float* x = (const float*)d_in[0];
  const float* Q = (const float*)d_in[1];
  float* out = (float*)d_out;

  bf16_t* xb = (bf16_t*)d_ws;                                        // 4 MB
  bf16_t* qb = (bf16_t*)((char*)d_ws + (size_t)B_ROWS * N_BITS * 2); // 8 MB

  prep_kernel<<<3072, 256, 0, stream>>>(x, Q, xb, qb, out);

  dim3 grid(N_BITS / BN, B_ROWS / BM, KSPLIT);  // (8, 8, 8) = 512 blocks
  qubo_kernel<<<grid, dim3(256), 0, stream>>>(xb, qb, out);
}